// Round 7
// baseline (16.139 us; speedup 1.0000x reference)
//
#include <hip/hip_runtime.h>

#define TOUT_ 481
#define EPS_  1e-8f

typedef __attribute__((ext_vector_type(8))) short bf16x8;
typedef __attribute__((ext_vector_type(4))) float f32x4;

__device__ __forceinline__ unsigned short f2bf(float f) {
  union { float f; unsigned u; } a; a.f = f;
  unsigned r = a.u + 0x7fffu + ((a.u >> 16) & 1u);
  return (unsigned short)(r >> 16);
}
__device__ __forceinline__ float bf2f(unsigned short h) {
  union { unsigned u; float f; } a; a.u = ((unsigned)h) << 16;
  return a.f;
}

// Grid: blockIdx = b*16 + c*2 + th. Block = 256 thr (4 waves).  [R5 structure]
// out[b,t,k2=4c+o] = pp(t,o) + min_s( kk[s,o] + sum_u A[t,u]*B[u,(s,o)] )
//   A[t,u] = bf16(xn[b, t+u, c]) (sliding window, K=32)
//   B[u,(so=s*4+o)] = bf16(-2*kn[s,4c+o,j]) for u = 8o+j, else 0
// kk folded into MFMA C-in. Main loop / frag / store verified R4/R5.
__global__ __launch_bounds__(256) void lsd_mfma4(
    const float* __restrict__ x, const float* __restrict__ kern,
    float* __restrict__ out) {
  __shared__ alignas(16) unsigned short Bls[2048];  // [so][j]: nonzero 8 bf16
  __shared__ float kkls[256];            // kk[so]
  __shared__ unsigned short lxb[544];    // bf16 xn channel c (zero-padded)
  __shared__ unsigned int   lxp[520];    // lxp[m] = (lxb[m], lxb[m+1])
  __shared__ float wsum[512];            // sliding sum of squares, window 8
  __shared__ float red[64];

  int tid  = threadIdx.x;
  int lane = tid & 63;
  int wv   = tid >> 6;
  int b    = blockIdx.x >> 4;
  int c    = (blockIdx.x >> 1) & 7;
  int th   = blockIdx.x & 1;

  // ---- kernel loads: 4 threads per s, PAIR-partitioned (pairs j≡q mod 4)
  //      so the owner's B pair (j = 4c+q, m = c) is among own loads ----
  int s = tid >> 2, q = tid & 3;
  const float4* kern4 = reinterpret_cast<const float4*>(kern);
  float4 kvA[16];
  #pragma unroll
  for (int m = 0; m < 8; ++m) {
    int j = q + 4 * m;                   // pair index within s (0..31)
    kvA[2 * m]     = kern4[s * 64 + 2 * j];
    kvA[2 * m + 1] = kern4[s * 64 + 2 * j + 1];
  }
  const float4* x4 = reinterpret_cast<const float4*>(x) + b * 1024;
  float4 xv[4];
  #pragma unroll
  for (int u = 0; u < 4; ++u) xv[u] = x4[tid + 256 * u];

  // ---- kernel stats (4 threads per s) ----
  float ksum = 0.f, ksq = 0.f;
  #pragma unroll
  for (int u = 0; u < 16; ++u) {
    float4 f = kvA[u];
    ksum += f.x + f.y + f.z + f.w;
    ksq = fmaf(f.x, f.x, ksq); ksq = fmaf(f.y, f.y, ksq);
    ksq = fmaf(f.z, f.z, ksq); ksq = fmaf(f.w, f.w, ksq);
  }
  ksum += __shfl_xor(ksum, 1, 64); ksq += __shfl_xor(ksq, 1, 64);
  ksum += __shfl_xor(ksum, 2, 64); ksq += __shfl_xor(ksq, 2, 64);
  float kmean = ksum * (1.0f / 256.0f);
  float kvar  = fmaxf(ksq * (1.0f / 256.0f) - kmean * kmean, 0.0f);
  float krstd = 1.0f / (sqrtf(kvar) + EPS_);

  // ---- B build: thread owns so = tid = 4s+q; pair already in kvA[2c] ----
  {
    float4 pa = kvA[2 * c], pb = kvA[2 * c + 1];
    float vv[8] = {pa.x, pa.y, pa.z, pa.w, pb.x, pb.y, pb.z, pb.w};
    union { unsigned u[4]; bf16x8 v; } bw;
    float kk = 0.f;
    #pragma unroll
    for (int jj = 0; jj < 4; ++jj) {
      float vn0 = (vv[2 * jj]     - kmean) * krstd;
      float vn1 = (vv[2 * jj + 1] - kmean) * krstd;
      unsigned short n0 = f2bf(-2.0f * vn0);
      unsigned short n1 = f2bf(-2.0f * vn1);
      float vq0 = bf2f(f2bf(vn0));
      float vq1 = bf2f(f2bf(vn1));
      kk = fmaf(vq0, vq0, kk);
      kk = fmaf(vq1, vq1, kk);
      bw.u[jj] = (unsigned)n0 | ((unsigned)n1 << 16);
    }
    *reinterpret_cast<bf16x8*>(&Bls[tid * 8]) = bw.v;   // conflict-free b128
    kkls[tid] = kk;
  }

  // ---- x channel stats: wave partials to red ----
  float4 s4v = {0, 0, 0, 0}, q4v = {0, 0, 0, 0};
  #pragma unroll
  for (int u = 0; u < 4; ++u) {
    s4v.x += xv[u].x; s4v.y += xv[u].y; s4v.z += xv[u].z; s4v.w += xv[u].w;
    q4v.x = fmaf(xv[u].x, xv[u].x, q4v.x); q4v.y = fmaf(xv[u].y, xv[u].y, q4v.y);
    q4v.z = fmaf(xv[u].z, xv[u].z, q4v.z); q4v.w = fmaf(xv[u].w, xv[u].w, q4v.w);
  }
  #pragma unroll
  for (int m = 2; m <= 32; m <<= 1) {
    s4v.x += __shfl_xor(s4v.x, m, 64); s4v.y += __shfl_xor(s4v.y, m, 64);
    s4v.z += __shfl_xor(s4v.z, m, 64); s4v.w += __shfl_xor(s4v.w, m, 64);
    q4v.x += __shfl_xor(q4v.x, m, 64); q4v.y += __shfl_xor(q4v.y, m, 64);
    q4v.z += __shfl_xor(q4v.z, m, 64); q4v.w += __shfl_xor(q4v.w, m, 64);
  }
  if (lane < 2) {
    int base = wv * 16 + lane * 8;
    red[base + 0] = s4v.x; red[base + 1] = s4v.y;
    red[base + 2] = s4v.z; red[base + 3] = s4v.w;
    red[base + 4] = q4v.x; red[base + 5] = q4v.y;
    red[base + 6] = q4v.z; red[base + 7] = q4v.w;
  }
  __syncthreads();                       // sync1: red + Bls/kkls

  // ---- per-thread channel-c stats from red (replaces cstat+sync2) ----
  float cm, cr;
  {
    int g = c >> 2, cp = c & 3;
    float sm = 0.f, sq = 0.f;
    #pragma unroll
    for (int w = 0; w < 4; ++w) {
      sm += red[w * 16 + g * 8 + cp];
      sq += red[w * 16 + g * 8 + 4 + cp];
    }
    cm = sm * (1.0f / 512.0f);
    float cva = fmaxf(sq * (1.0f / 512.0f) - cm * cm, 0.0f);
    cr = 1.0f / (sqrtf(cva) + EPS_);
  }

  // ---- bf16 normalized channel from registers ----
  if ((tid & 1) == (c >> 2)) {
    #pragma unroll
    for (int u = 0; u < 4; ++u) {
      int t = (tid >> 1) + 128 * u;
      float4 f = xv[u];
      float val = (c & 2) ? ((c & 1) ? f.w : f.z) : ((c & 1) ? f.y : f.x);
      lxb[t] = f2bf((val - cm) * cr);
    }
  }
  if (tid < 32) lxb[512 + tid] = 0;

  // ---- B fragments + prebuilt C-in (Bls/kkls stable since sync1) ----
  int l15 = lane & 15, kch = lane >> 4;
  bool match = (kch == (l15 & 3));
  bf16x8 Bf[16];
  f32x4  cin[16];
  #pragma unroll
  for (int g = 0; g < 16; ++g) {
    int so = g * 16 + l15;
    bf16x8 z = {0, 0, 0, 0, 0, 0, 0, 0};
    Bf[g] = match ? *reinterpret_cast<const bf16x8*>(&Bls[so * 8]) : z;
    float kkv = kkls[so];
    cin[g][0] = kkv; cin[g][1] = kkv; cin[g][2] = kkv; cin[g][3] = kkv;
  }
  __syncthreads();                       // sync2: lxb

  // ---- pair table + sliding sum of squares ----
  for (int i = tid; i < 520; i += 256)
    lxp[i] = (unsigned)lxb[i] | ((unsigned)lxb[i + 1] << 16);
  for (int m = tid; m < 512; m += 256) {
    float acc = 0.f;
    #pragma unroll
    for (int j = 0; j < 8; ++j) { float v = bf2f(lxb[m + j]); acc = fmaf(v, v, acc); }
    wsum[m] = acc;
  }
  __syncthreads();                       // sync3: lxp/wsum

  // ---- main loop (R4/R5-verified): 16 MFMA + mins per 16-row t-tile ----
  int NT = th ? 15 : 16;
  int la = l15 + 8 * kch;                // A element offset = row + k-chunk*8
  for (int gt = wv; gt < NT; gt += 4) {
    int t0 = th * 248 + gt * 16;
    int p  = t0 + la;
    union { unsigned ui[4]; bf16x8 v; } au;
    au.ui[0] = lxp[p];     au.ui[1] = lxp[p + 2];
    au.ui[2] = lxp[p + 4]; au.ui[3] = lxp[p + 6];

    f32x4 mn = {3.0e38f, 3.0e38f, 3.0e38f, 3.0e38f};
    #pragma unroll
    for (int g = 0; g < 16; ++g) {
      f32x4 d = __builtin_amdgcn_mfma_f32_16x16x32_bf16(au.v, Bf[g], cin[g], 0, 0, 0);
      mn[0] = fminf(mn[0], d[0]); mn[1] = fminf(mn[1], d[1]);
      mn[2] = fminf(mn[2], d[2]); mn[3] = fminf(mn[3], d[3]);
    }
    #pragma unroll
    for (int r = 0; r < 4; ++r) {
      mn[r] = fminf(mn[r], __shfl_xor(mn[r], 4, 64));
      mn[r] = fminf(mn[r], __shfl_xor(mn[r], 8, 64));
    }
    int o = lane & 3;
    float ma = (lane & 4) ? mn[1] : mn[0];
    float mb = (lane & 4) ? mn[3] : mn[2];
    float mv = (lane & 8) ? mb : ma;
    int t = t0 + (lane >> 4) * 4 + ((lane >> 2) & 3);
    if (t < TOUT_)
      out[(b * TOUT_ + t) * 32 + c * 4 + o] = wsum[t + 8 * o] + mv;
  }
}

extern "C" void kernel_launch(void* const* d_in, const int* in_sizes, int n_in,
                              void* d_out, int out_size, void* d_ws, size_t ws_size,
                              hipStream_t stream) {
  const float* x    = (const float*)d_in[0];
  const float* kern = (const float*)d_in[1];
  float* out = (float*)d_out;
  lsd_mfma4<<<256, 256, 0, stream>>>(x, kern, out);
}

// Round 8
// 13.392 us; speedup vs baseline: 1.2051x; 1.2051x over previous
//
#include <hip/hip_runtime.h>

#define TOUT_ 481
#define EPS_  1e-8f

typedef __attribute__((ext_vector_type(8))) short bf16x8;
typedef __attribute__((ext_vector_type(4))) float f32x4;

__device__ __forceinline__ unsigned short f2bf(float f) {
  union { float f; unsigned u; } a; a.f = f;
  unsigned r = a.u + 0x7fffu + ((a.u >> 16) & 1u);
  return (unsigned short)(r >> 16);
}
__device__ __forceinline__ float bf2f(unsigned short h) {
  union { unsigned u; float f; } a; a.u = ((unsigned)h) << 16;
  return a.f;
}

// Grid: blockIdx = b*16 + c*2 + th. Block = 256 thr (4 waves).
// out[b,t,k2=4c+o] = pp(t,o) + min_s( kk[s,o] + sum_u A[t,u]*B[u,(s,o)] )
//   A[t,u] = bf16(xn[b, t+u, c]) (sliding window, K=32)
//   B[u,(so=s*4+o)] = bf16(-2*kn[s,4c+o,j]) for u = 8o+j, else 0
// kk folded into MFMA C-in (per-col broadcast). EXACT R5 source (best: 13.40).
__global__ __launch_bounds__(256) void lsd_mfma2(
    const float* __restrict__ x, const float* __restrict__ kern,
    float* __restrict__ out) {
  __shared__ alignas(16) unsigned short Bls[2048];  // [so][j]: nonzero 8 bf16
  __shared__ float kkls[256];            // kk[so]
  __shared__ unsigned short lxb[544];    // bf16 xn channel c (zero-padded)
  __shared__ unsigned int   lxp[520];    // lxp[m] = (lxb[m], lxb[m+1])
  __shared__ float wsum[512];            // sliding sum of squares, window 8
  __shared__ float red[64];
  __shared__ float cstat[16];

  int tid  = threadIdx.x;
  int lane = tid & 63;
  int wv   = tid >> 6;
  int b    = blockIdx.x >> 4;
  int c    = (blockIdx.x >> 1) & 7;
  int th   = blockIdx.x & 1;

  // ---- global loads (early issue) ----
  int s = tid >> 2, q = tid & 3;
  const float4* kern4 = reinterpret_cast<const float4*>(kern);
  float4 kv[16];
  #pragma unroll
  for (int u = 0; u < 16; ++u) kv[u] = kern4[s * 64 + q * 16 + u];

  const float4* x4 = reinterpret_cast<const float4*>(x) + b * 1024;
  float4 xv[4];
  #pragma unroll
  for (int u = 0; u < 4; ++u) xv[u] = x4[tid + 256 * u];

  int k2 = 4 * c + q;                    // this thread's owned column data
  float4 kb0 = kern4[s * 64 + k2 * 2];
  float4 kb1 = kern4[s * 64 + k2 * 2 + 1];

  // ---- kernel stats (4 threads per s; owner's s == stats s) ----
  float ksum = 0.f, ksq = 0.f;
  #pragma unroll
  for (int u = 0; u < 16; ++u) {
    ksum += kv[u].x + kv[u].y + kv[u].z + kv[u].w;
    ksq = fmaf(kv[u].x, kv[u].x, ksq); ksq = fmaf(kv[u].y, kv[u].y, ksq);
    ksq = fmaf(kv[u].z, kv[u].z, ksq); ksq = fmaf(kv[u].w, kv[u].w, ksq);
  }
  ksum += __shfl_xor(ksum, 1, 64); ksq += __shfl_xor(ksq, 1, 64);
  ksum += __shfl_xor(ksum, 2, 64); ksq += __shfl_xor(ksq, 2, 64);
  float kmean = ksum * (1.0f / 256.0f);
  float kvar  = fmaxf(ksq * (1.0f / 256.0f) - kmean * kmean, 0.0f);
  float krstd = 1.0f / (sqrtf(kvar) + EPS_);

  // ---- B build: thread owns so = tid = 4s+q; stats already in regs ----
  {
    float vv[8] = {kb0.x, kb0.y, kb0.z, kb0.w, kb1.x, kb1.y, kb1.z, kb1.w};
    union { unsigned u[4]; bf16x8 v; } bw;
    float kk = 0.f;
    #pragma unroll
    for (int jj = 0; jj < 4; ++jj) {
      float vn0 = (vv[2 * jj]     - kmean) * krstd;
      float vn1 = (vv[2 * jj + 1] - kmean) * krstd;
      unsigned short n0 = f2bf(-2.0f * vn0);   // == bits of -2*quantized(vn0)
      unsigned short n1 = f2bf(-2.0f * vn1);
      float vq0 = bf2f(f2bf(vn0));
      float vq1 = bf2f(f2bf(vn1));
      kk = fmaf(vq0, vq0, kk);
      kk = fmaf(vq1, vq1, kk);
      bw.u[jj] = (unsigned)n0 | ((unsigned)n1 << 16);
    }
    *reinterpret_cast<bf16x8*>(&Bls[tid * 8]) = bw.v;   // conflict-free b128
    kkls[tid] = kk;
  }

  // ---- x channel stats (R2/R4-verified pattern) ----
  float4 s4v = {0, 0, 0, 0}, q4v = {0, 0, 0, 0};
  #pragma unroll
  for (int u = 0; u < 4; ++u) {
    s4v.x += xv[u].x; s4v.y += xv[u].y; s4v.z += xv[u].z; s4v.w += xv[u].w;
    q4v.x = fmaf(xv[u].x, xv[u].x, q4v.x); q4v.y = fmaf(xv[u].y, xv[u].y, q4v.y);
    q4v.z = fmaf(xv[u].z, xv[u].z, q4v.z); q4v.w = fmaf(xv[u].w, xv[u].w, q4v.w);
  }
  #pragma unroll
  for (int m = 2; m <= 32; m <<= 1) {
    s4v.x += __shfl_xor(s4v.x, m, 64); s4v.y += __shfl_xor(s4v.y, m, 64);
    s4v.z += __shfl_xor(s4v.z, m, 64); s4v.w += __shfl_xor(s4v.w, m, 64);
    q4v.x += __shfl_xor(q4v.x, m, 64); q4v.y += __shfl_xor(q4v.y, m, 64);
    q4v.z += __shfl_xor(q4v.z, m, 64); q4v.w += __shfl_xor(q4v.w, m, 64);
  }
  if (lane < 2) {
    int base = wv * 16 + lane * 8;
    red[base + 0] = s4v.x; red[base + 1] = s4v.y;
    red[base + 2] = s4v.z; red[base + 3] = s4v.w;
    red[base + 4] = q4v.x; red[base + 5] = q4v.y;
    red[base + 6] = q4v.z; red[base + 7] = q4v.w;
  }
  __syncthreads();                       // sync1: red (Bls/kkls also covered)
  if (tid < 8) {
    int g = tid >> 2, cp = tid & 3;
    float sm = 0.f, sq = 0.f;
    #pragma unroll
    for (int w = 0; w < 4; ++w) {
      sm += red[w * 16 + g * 8 + cp];
      sq += red[w * 16 + g * 8 + 4 + cp];
    }
    float mean = sm * (1.0f / 512.0f);
    float var  = fmaxf(sq * (1.0f / 512.0f) - mean * mean, 0.0f);
    cstat[tid]     = mean;
    cstat[8 + tid] = 1.0f / (sqrtf(var) + EPS_);
  }
  __syncthreads();                       // sync2: cstat

  // ---- bf16 normalized channel from registers (R4-verified) ----
  if ((tid & 1) == (c >> 2)) {
    float cm = cstat[c], cr = cstat[8 + c];
    #pragma unroll
    for (int u = 0; u < 4; ++u) {
      int t = (tid >> 1) + 128 * u;
      float4 f = xv[u];
      float val = (c & 2) ? ((c & 1) ? f.w : f.z) : ((c & 1) ? f.y : f.x);
      lxb[t] = f2bf((val - cm) * cr);
    }
  }
  if (tid < 32) lxb[512 + tid] = 0;
  __syncthreads();                       // sync3: lxb

  // ---- B fragments + prebuilt C-in (Bls/kkls visible since sync1) ----
  int l15 = lane & 15, kch = lane >> 4;
  bool match = (kch == (l15 & 3));
  bf16x8 Bf[16];
  f32x4  cin[16];
  #pragma unroll
  for (int g = 0; g < 16; ++g) {
    int so = g * 16 + l15;
    bf16x8 z = {0, 0, 0, 0, 0, 0, 0, 0};
    Bf[g] = match ? *reinterpret_cast<const bf16x8*>(&Bls[so * 8]) : z;
    float kkv = kkls[so];
    cin[g][0] = kkv; cin[g][1] = kkv; cin[g][2] = kkv; cin[g][3] = kkv;
  }

  // ---- pair table + sliding sum of squares ----
  for (int i = tid; i < 520; i += 256)
    lxp[i] = (unsigned)lxb[i] | ((unsigned)lxb[i + 1] << 16);
  for (int m = tid; m < 512; m += 256) {
    float acc = 0.f;
    #pragma unroll
    for (int j = 0; j < 8; ++j) { float v = bf2f(lxb[m + j]); acc = fmaf(v, v, acc); }
    wsum[m] = acc;
  }
  __syncthreads();                       // sync4: lxp/wsum

  // ---- main loop (R4-verified): 16 MFMA + mins per 16-row t-tile ----
  int NT = th ? 15 : 16;
  int la = l15 + 8 * kch;                // A element offset = row + k-chunk*8
  for (int gt = wv; gt < NT; gt += 4) {
    int t0 = th * 248 + gt * 16;
    int p  = t0 + la;
    union { unsigned ui[4]; bf16x8 v; } au;
    au.ui[0] = lxp[p];     au.ui[1] = lxp[p + 2];
    au.ui[2] = lxp[p + 4]; au.ui[3] = lxp[p + 6];

    f32x4 mn = {3.0e38f, 3.0e38f, 3.0e38f, 3.0e38f};
    #pragma unroll
    for (int g = 0; g < 16; ++g) {
      f32x4 d = __builtin_amdgcn_mfma_f32_16x16x32_bf16(au.v, Bf[g], cin[g], 0, 0, 0);
      mn[0] = fminf(mn[0], d[0]); mn[1] = fminf(mn[1], d[1]);
      mn[2] = fminf(mn[2], d[2]); mn[3] = fminf(mn[3], d[3]);
    }
    #pragma unroll
    for (int r = 0; r < 4; ++r) {
      mn[r] = fminf(mn[r], __shfl_xor(mn[r], 4, 64));
      mn[r] = fminf(mn[r], __shfl_xor(mn[r], 8, 64));
    }
    int o = lane & 3;
    float ma = (lane & 4) ? mn[1] : mn[0];
    float mb = (lane & 4) ? mn[3] : mn[2];
    float mv = (lane & 8) ? mb : ma;
    int t = t0 + (lane >> 4) * 4 + ((lane >> 2) & 3);
    if (t < TOUT_)
      out[(b * TOUT_ + t) * 32 + c * 4 + o] = wsum[t + 8 * o] + mv;
  }
}

extern "C" void kernel_launch(void* const* d_in, const int* in_sizes, int n_in,
                              void* d_out, int out_size, void* d_ws, size_t ws_size,
                              hipStream_t stream) {
  const float* x    = (const float*)d_in[0];
  const float* kern = (const float*)d_in[1];
  float* out = (float*)d_out;
  lsd_mfma2<<<256, 256, 0, stream>>>(x, kern, out);
}